// Round 1
// baseline (346.227 us; speedup 1.0000x reference)
//
#include <hip/hip_runtime.h>
#include <hip/hip_bf16.h>

// TasteNet fused MLP: z(N,64) -> h1(128) relu -> h2(128) relu -> b(12) ->
// clamp/taste/segment-sum epilogue with x(N,9) -> out(N,3) fp32.
//
// Strategy: transposed MFMA chain C[feat][row] = Wt x dataT, bf16 32x32x16.
// Weights (transposed, bf16, bias folded as K-column vs constant-1 B-frag)
// live in LDS (~62 KB/block). Intermediate h stays in registers: the C/D
// layout converts to the next layer's B-operand layout with one
// v_permlane32_swap_b32 per packed register pair. No LDS round-trip for h,
// no __syncthreads after weight staging.

typedef __bf16 bf16x8 __attribute__((ext_vector_type(8)));
typedef float  f32x16 __attribute__((ext_vector_type(16)));
typedef unsigned int uint2v __attribute__((ext_vector_type(2)));
typedef unsigned int uint4v __attribute__((ext_vector_type(4)));

#define MFMA32(a, b, c) __builtin_amdgcn_mfma_f32_32x32x16_bf16((a), (b), (c), 0, 0, 0)

// LDS element offsets (__bf16 units). Strides: W1t=72 (64 K + bias + slack),
// W2t/W3t=136 (128 K + bias + slack). Overreads at kt=bias,q=1 land in the
// next array / tail pad and are multiplied by B=0 (zero-initialized LDS).
#define SW3_OFF 0              // 32 rows x 136
#define SW1_OFF 4352           // 128 rows x 72
#define SW2_OFF 13568          // 128 rows x 136
#define SMEM_ELTS 31008        // = 30976 + 32 tail pad (61.6 KB)

#define NBLK  512
#define WPB   4
#define ITERS 8                // 512*4*32*8 = 524288 rows

__device__ __forceinline__ unsigned pkbf(float lo, float hi) {
  unsigned short lb = __builtin_bit_cast(unsigned short, (__bf16)lo);
  unsigned short hb = __builtin_bit_cast(unsigned short, (__bf16)hi);
  return ((unsigned)hb << 16) | (unsigned)lb;
}

// Build layer-(i+1) B-fragment (k = kt*16 + (lane>>5)*8 + j, n = lane&31)
// from layer-i C-layout accumulator h (feats (reg&3)+8*(reg>>2)+4*(lane>>5)).
// Derivation: element j needs reg (j&3)+4*(lane>>5)+8*SUB from lane-half j>>2.
// With packed pairs p01=(r0,r1).. the exchange is exactly permlane32_swap.
template <int SUB>
__device__ __forceinline__ bf16x8 mk_bfrag(const f32x16 h) {
  constexpr int B = SUB * 8;
  unsigned p01 = pkbf(h[B + 0], h[B + 1]);
  unsigned p23 = pkbf(h[B + 2], h[B + 3]);
  unsigned p45 = pkbf(h[B + 4], h[B + 5]);
  unsigned p67 = pkbf(h[B + 6], h[B + 7]);
  unsigned d0, d1, d2, d3;
#if __has_builtin(__builtin_amdgcn_permlane32_swap)
  uint2v r1 = __builtin_amdgcn_permlane32_swap(p01, p45, false, false);
  uint2v r2 = __builtin_amdgcn_permlane32_swap(p23, p67, false, false);
  d0 = r1[0]; d2 = r1[1];
  d1 = r2[0]; d3 = r2[1];
#else
  int hi = (threadIdx.x >> 5) & 1;
  unsigned sp01 = (unsigned)__shfl_xor((int)p01, 32, 64);
  unsigned sp23 = (unsigned)__shfl_xor((int)p23, 32, 64);
  unsigned sp45 = (unsigned)__shfl_xor((int)p45, 32, 64);
  unsigned sp67 = (unsigned)__shfl_xor((int)p67, 32, 64);
  d0 = hi ? sp45 : p01;   // e0,e1 = [p01.lo, p45.lo]
  d2 = hi ? p45  : sp01;  // e4,e5 = [p01.hi, p45.hi]
  d1 = hi ? sp67 : p23;
  d3 = hi ? p67  : sp23;
#endif
  uint4v t; t[0] = d0; t[1] = d1; t[2] = d2; t[3] = d3;
  return __builtin_bit_cast(bf16x8, t);
}

__device__ __forceinline__ bf16x8 ldsA(const __bf16* sm, int off) {
  return *(const bf16x8*)(sm + off);
}

__global__ __launch_bounds__(256, 2)
void tastenet_kernel(const float* __restrict__ x, const float* __restrict__ z,
                     const float* __restrict__ W1, const float* __restrict__ b1,
                     const float* __restrict__ W2, const float* __restrict__ b2,
                     const float* __restrict__ W3, const float* __restrict__ b3,
                     float* __restrict__ out) {
  __shared__ __align__(16) __bf16 sm[SMEM_ELTS];
  const int tid = threadIdx.x;

  // ---- stage weights: zero all (pad cols must be 0), then fill transposed ----
  for (int i = tid; i < SMEM_ELTS / 2; i += 256) ((unsigned*)sm)[i] = 0u;
  __syncthreads();
  for (int i = tid; i < 64 * 128; i += 256) {
    int k = i >> 7, m = i & 127;
    sm[SW1_OFF + m * 72 + k] = (__bf16)W1[i];
  }
  if (tid < 128) sm[SW1_OFF + tid * 72 + 64] = (__bf16)b1[tid];
  for (int i = tid; i < 128 * 128; i += 256) {
    int k = i >> 7, m = i & 127;
    sm[SW2_OFF + m * 136 + k] = (__bf16)W2[i];
  }
  if (tid < 128) sm[SW2_OFF + tid * 136 + 128] = (__bf16)b2[tid];
  for (int i = tid; i < 128 * 12; i += 256) {
    int k = i / 12, m = i - k * 12;
    sm[SW3_OFF + m * 136 + k] = (__bf16)W3[i];
  }
  if (tid < 12) sm[SW3_OFF + tid * 136 + 128] = (__bf16)b3[tid];
  __syncthreads();

  const int wave = tid >> 6;
  const int lane = tid & 63;
  const int q    = lane >> 5;   // wave half
  const int n    = lane & 31;   // data row within 32-row tile

  // constant-1 B-fragment for the bias K-column (k==64 / k==128 -> q=0, j=0)
  bf16x8 bias_frag;
  #pragma unroll
  for (int i = 0; i < 8; ++i) bias_frag[i] = (__bf16)0.0f;
  if (q == 0) bias_frag[0] = (__bf16)1.0f;

  const int a1base = SW1_OFF + n * 72  + q * 8;  // + ft*32*72  + kt*16
  const int a2base = SW2_OFF + n * 136 + q * 8;  // + ft*32*136 + kt*16
  const int a3base = SW3_OFF + n * 136 + q * 8;  // + kt*16

  const long tile0 = (long)blockIdx.x * WPB + wave;

  // prefetch z for first tile (B-operand: 8 contiguous floats per lane)
  float4 zv[8];
  {
    const float* zr = z + (tile0 * 32 + n) * 64;
    #pragma unroll
    for (int kt = 0; kt < 4; ++kt) {
      zv[2 * kt]     = *(const float4*)(zr + kt * 16 + q * 8);
      zv[2 * kt + 1] = *(const float4*)(zr + kt * 16 + q * 8 + 4);
    }
  }

  for (int it = 0; it < ITERS; ++it) {
    const long tile = (long)it * (NBLK * WPB) + tile0;
    const long row  = tile * 32 + n;

    // convert staged z to bf16 B-frags
    bf16x8 bz[4];
    #pragma unroll
    for (int kt = 0; kt < 4; ++kt) {
      float4 a = zv[2 * kt], b = zv[2 * kt + 1];
      bf16x8 f;
      f[0] = (__bf16)a.x; f[1] = (__bf16)a.y; f[2] = (__bf16)a.z; f[3] = (__bf16)a.w;
      f[4] = (__bf16)b.x; f[5] = (__bf16)b.y; f[6] = (__bf16)b.z; f[7] = (__bf16)b.w;
      bz[kt] = f;
    }
    // prefetch next tile's z (hides HBM latency under layers 1-3)
    if (it + 1 < ITERS) {
      const float* zr = z + ((tile + NBLK * WPB) * 32 + n) * 64;
      #pragma unroll
      for (int kt = 0; kt < 4; ++kt) {
        zv[2 * kt]     = *(const float4*)(zr + kt * 16 + q * 8);
        zv[2 * kt + 1] = *(const float4*)(zr + kt * 16 + q * 8 + 4);
      }
    }

    // ---- layer 1: h1T[128][32] = W1t x zT, relu ----
    f32x16 h1[4];
    #pragma unroll
    for (int ft = 0; ft < 4; ++ft) {
      f32x16 acc;
      #pragma unroll
      for (int i = 0; i < 16; ++i) acc[i] = 0.0f;
      #pragma unroll
      for (int kt = 0; kt < 4; ++kt)
        acc = MFMA32(ldsA(sm, a1base + ft * (32 * 72) + kt * 16), bz[kt], acc);
      acc = MFMA32(ldsA(sm, a1base + ft * (32 * 72) + 64), bias_frag, acc);
      #pragma unroll
      for (int i = 0; i < 16; ++i) acc[i] = fmaxf(acc[i], 0.0f);
      h1[ft] = acc;
    }

    // ---- layer 2: h2T = W2t x h1T, relu (h1 consumed from registers) ----
    f32x16 acc2[4];
    #pragma unroll
    for (int ft = 0; ft < 4; ++ft) {
      #pragma unroll
      for (int i = 0; i < 16; ++i) acc2[ft][i] = 0.0f;
    }
    #pragma unroll
    for (int kt = 0; kt < 8; ++kt) {
      bf16x8 bf = (kt & 1) ? mk_bfrag<1>(h1[kt >> 1]) : mk_bfrag<0>(h1[kt >> 1]);
      #pragma unroll
      for (int ft = 0; ft < 4; ++ft)
        acc2[ft] = MFMA32(ldsA(sm, a2base + ft * (32 * 136) + kt * 16), bf, acc2[ft]);
    }
    #pragma unroll
    for (int ft = 0; ft < 4; ++ft) {
      acc2[ft] = MFMA32(ldsA(sm, a2base + ft * (32 * 136) + 128), bias_frag, acc2[ft]);
      #pragma unroll
      for (int i = 0; i < 16; ++i) acc2[ft][i] = fmaxf(acc2[ft][i], 0.0f);
    }

    // ---- layer 3: bT[12(pad32)][32] = W3t x h2T ----
    f32x16 acc3;
    #pragma unroll
    for (int i = 0; i < 16; ++i) acc3[i] = 0.0f;
    #pragma unroll
    for (int kt = 0; kt < 8; ++kt) {
      bf16x8 bf = (kt & 1) ? mk_bfrag<1>(acc2[kt >> 1]) : mk_bfrag<0>(acc2[kt >> 1]);
      acc3 = MFMA32(ldsA(sm, a3base + kt * 16), bf, acc3);
    }
    acc3 = MFMA32(ldsA(sm, a3base + 128), bias_frag, acc3);

    // ---- epilogue ----
    // q=0 lane holds feats {0,1,2,3, 8,9,10,11} in regs 0..7; q=1 holds {4..7} in 0..3.
    // clamp (min 0): feats 0..5,7,8; pass: 6 and intercepts 9..11.
    float t0 = acc3[0], t1 = acc3[1], t2 = acc3[2], t3 = acc3[3];
    float t4 = acc3[4], t5 = acc3[5], t6 = acc3[6], t7 = acc3[7];
    const float* xr = x + row * 9;
    float o0 = 0.f, o1 = 0.f, o2 = 0.f, g1 = 0.f, g2 = 0.f;
    if (q == 0) {
      t0 = fminf(t0, 0.0f); t1 = fminf(t1, 0.0f);
      t2 = fminf(t2, 0.0f); t3 = fminf(t3, 0.0f);
      t4 = fminf(t4, 0.0f);                      // feat 8
      float x0 = xr[0], x1 = xr[1], x2 = xr[2], x3 = xr[3], x8 = xr[8];
      o0 = x0 * t0 + x1 * t1 + x2 * t2 + t5;     // seg0 + I9
      o1 = x3 * t3 + t6;                         // seg1 part + I10
      o2 = x8 * t4 + t7;                         // seg2 part + I11
    } else {
      t0 = fminf(t0, 0.0f); t1 = fminf(t1, 0.0f);  // feats 4,5
      t3 = fminf(t3, 0.0f);                        // feat 7 (feat 6 = t2 passes)
      float x4 = xr[4], x5 = xr[5], x6 = xr[6], x7 = xr[7];
      g1 = x4 * t0 + x5 * t1;
      g2 = x6 * t2 + x7 * t3;
    }
    float a1v = __shfl_xor(g1, 32, 64);
    float a2v = __shfl_xor(g2, 32, 64);
    if (q == 0) {
      float* op = out + row * 3;
      op[0] = o0;
      op[1] = o1 + a1v;
      op[2] = o2 + a2v;
    }
  }
}

extern "C" void kernel_launch(void* const* d_in, const int* in_sizes, int n_in,
                              void* d_out, int out_size, void* d_ws, size_t ws_size,
                              hipStream_t stream) {
  const float* x  = (const float*)d_in[0];
  const float* z  = (const float*)d_in[1];
  const float* W1 = (const float*)d_in[2];
  const float* b1 = (const float*)d_in[3];
  const float* W2 = (const float*)d_in[4];
  const float* b2 = (const float*)d_in[5];
  const float* W3 = (const float*)d_in[6];
  const float* b3 = (const float*)d_in[7];
  tastenet_kernel<<<dim3(NBLK), dim3(256), 0, stream>>>(
      x, z, W1, b1, W2, b2, W3, b3, (float*)d_out);
}